// Round 1
// baseline (4378.573 us; speedup 1.0000x reference)
//
#include <hip/hip_runtime.h>
#include <hip/hip_bf16.h>
#include <cstdint>
#include <cstddef>

#define B_ 2
#define T_ 2048
#define C_ 1024
#define H_ 16
#define HD_ 64
#define FF_ 4096
#define BT_ (B_*T_)   // 4096 rows

// ---------------------------------------------------------------------------
// LayerNorm: one block (256 threads) per row of C_=1024. float4 per thread.
// ---------------------------------------------------------------------------
__global__ __launch_bounds__(256) void ln_kernel(const float* __restrict__ x,
                                                 const float* __restrict__ g,
                                                 const float* __restrict__ b,
                                                 float* __restrict__ out) {
    int row = blockIdx.x;
    int tid = threadIdx.x;
    const float* xr = x + (size_t)row * C_;
    float4 v = *(const float4*)(xr + tid * 4);
    float s = v.x + v.y + v.z + v.w;
    float q = v.x*v.x + v.y*v.y + v.z*v.z + v.w*v.w;
    #pragma unroll
    for (int off = 32; off > 0; off >>= 1) {
        s += __shfl_down(s, off);
        q += __shfl_down(q, off);
    }
    __shared__ float ss[4], qs[4];
    if ((tid & 63) == 0) { ss[tid >> 6] = s; qs[tid >> 6] = q; }
    __syncthreads();
    s = ss[0] + ss[1] + ss[2] + ss[3];
    q = qs[0] + qs[1] + qs[2] + qs[3];
    float mu  = s * (1.0f / C_);
    float var = q * (1.0f / C_) - mu * mu;
    float r = rsqrtf(var + 1e-5f);
    float4 gv = *(const float4*)(g + tid * 4);
    float4 bv = *(const float4*)(b + tid * 4);
    float4 o;
    o.x = (v.x - mu) * r * gv.x + bv.x;
    o.y = (v.y - mu) * r * gv.y + bv.y;
    o.z = (v.z - mu) * r * gv.z + bv.z;
    o.w = (v.w - mu) * r * gv.w + bv.w;
    *(float4*)(out + (size_t)row * C_ + tid * 4) = o;
}

// ---------------------------------------------------------------------------
// Generic fp32 tiled GEMM.  C[M,N] = epilogue(A[M,K] @ B[K,N])
// 256 threads, thread grid 16x16, each thread TMxTN outputs.
// BK=16. z-batching via bsB (B pointer stride) and bsC (C pointer stride).
// EPI bits: 1=bias, 2=relu, 4=residual (resid has same ldc layout as C).
// ---------------------------------------------------------------------------
template<int BM, int BN, int TM, int TN, int EPI>
__global__ __launch_bounds__(256) void gemm_kernel(
    const float* __restrict__ A, int lda,
    const float* __restrict__ Bmat, int ldb, long bsB,
    float* __restrict__ Cmat, int ldc, long bsC,
    const float* __restrict__ bias,
    const float* __restrict__ resid,
    int M, int N, int K)
{
    constexpr int BK = 16;
    __shared__ float As[BK][BM + 4];   // k-major so a[i] reads are contiguous
    __shared__ float Bs[BK][BN + 4];

    int tid = threadIdx.x;
    int tc = tid & 15;    // col group 0..15
    int tr = tid >> 4;    // row group 0..15
    int m0 = blockIdx.y * BM;
    int n0 = blockIdx.x * BN;
    const float* Bp = Bmat + (size_t)blockIdx.z * bsB;
    float*       Cp = Cmat + (size_t)blockIdx.z * bsC;

    float acc[TM][TN];
    #pragma unroll
    for (int i = 0; i < TM; i++)
        #pragma unroll
        for (int j = 0; j < TN; j++) acc[i][j] = 0.f;

    for (int k0 = 0; k0 < K; k0 += BK) {
        __syncthreads();
        // stage A tile (BM x BK) into k-major LDS
        for (int i = tid; i < BM * BK; i += 256) {
            int r = i >> 4;      // 0..BM-1
            int c = i & 15;      // 0..15
            As[c][r] = A[(size_t)(m0 + r) * lda + k0 + c];
        }
        // stage B tile (BK x BN)
        for (int i = tid; i < BK * BN; i += 256) {
            int r = i / BN;
            int c = i % BN;
            Bs[r][c] = Bp[(size_t)(k0 + r) * ldb + n0 + c];
        }
        __syncthreads();
        #pragma unroll
        for (int kk = 0; kk < BK; kk++) {
            float a[TM], bb[TN];
            #pragma unroll
            for (int i = 0; i < TM; i++) a[i] = As[kk][tr * TM + i];
            #pragma unroll
            for (int j = 0; j < TN; j++) bb[j] = Bs[kk][tc * TN + j];
            #pragma unroll
            for (int i = 0; i < TM; i++)
                #pragma unroll
                for (int j = 0; j < TN; j++)
                    acc[i][j] += a[i] * bb[j];
        }
    }

    #pragma unroll
    for (int i = 0; i < TM; i++) {
        int row = m0 + tr * TM + i;
        #pragma unroll
        for (int j = 0; j < TN; j++) {
            int col = n0 + tc * TN + j;
            float v = acc[i][j];
            if (EPI & 1) v += bias[col];
            if (EPI & 2) v = fmaxf(v, 0.f);
            if (EPI & 4) v += resid[(size_t)row * ldc + col];
            Cp[(size_t)row * ldc + col] = v;
        }
    }
}

// ---------------------------------------------------------------------------
// Causal flash attention, fp32. One thread per query row (t), 256 threads per
// block -> 256 consecutive rows per (b,h). K/V tiles (64x64) staged in LDS;
// inner-loop reads are wave-broadcast (all lanes same LDS address).
// qkv layout: [BT_][3072], q at col h*64, k at 1024+h*64, v at 2048+h*64.
// ---------------------------------------------------------------------------
__global__ __launch_bounds__(256) void attn_kernel(const float* __restrict__ qkv,
                                                   float* __restrict__ attn_out) {
    int bh = blockIdx.y;          // 0..31
    int bb = bh >> 4;             // batch
    int head = bh & 15;
    int t = blockIdx.x * 256 + threadIdx.x;

    const float* qp = qkv + ((size_t)(bb * T_ + t)) * 3072 + head * 64;
    float q[64];
    #pragma unroll
    for (int i = 0; i < 16; i++) {
        float4 v = *(const float4*)(qp + i * 4);
        q[4*i+0] = v.x * 0.125f;  // HD^-0.5 = 1/8
        q[4*i+1] = v.y * 0.125f;
        q[4*i+2] = v.z * 0.125f;
        q[4*i+3] = v.w * 0.125f;
    }
    float m = -INFINITY, l = 0.f;
    float acc[64];
    #pragma unroll
    for (int d = 0; d < 64; d++) acc[d] = 0.f;

    __shared__ float Ks[64][64];
    __shared__ float Vs[64][64];

    int nk = blockIdx.x * 256 + 256;   // keys needed by this block (<= T_)

    for (int s0 = 0; s0 < nk; s0 += 64) {
        __syncthreads();
        #pragma unroll
        for (int i = 0; i < 4; i++) {
            int flat = threadIdx.x + 256 * i;        // 0..1023
            int sr = flat >> 4;
            int c4 = (flat & 15) * 4;
            size_t kb = ((size_t)(bb * T_ + s0 + sr)) * 3072 + 1024 + head * 64 + c4;
            float4 kv = *(const float4*)(qkv + kb);
            float4 vv = *(const float4*)(qkv + kb + 1024);
            *(float4*)&Ks[sr][c4] = kv;
            *(float4*)&Vs[sr][c4] = vv;
        }
        __syncthreads();
        int send = (nk - s0 < 64) ? (nk - s0) : 64;
        for (int sl = 0; sl < send; sl++) {
            if (s0 + sl > t) break;   // causal; remaining keys also masked
            float p0 = 0.f, p1 = 0.f, p2 = 0.f, p3 = 0.f;
            #pragma unroll
            for (int d = 0; d < 64; d += 4) {
                p0 += q[d+0] * Ks[sl][d+0];
                p1 += q[d+1] * Ks[sl][d+1];
                p2 += q[d+2] * Ks[sl][d+2];
                p3 += q[d+3] * Ks[sl][d+3];
            }
            float sc = (p0 + p1) + (p2 + p3);
            if (sc > m) {               // rare rescale
                float corr = __expf(m - sc);
                m = sc;
                l *= corr;
                #pragma unroll
                for (int d = 0; d < 64; d++) acc[d] *= corr;
            }
            float p = __expf(sc - m);
            l += p;
            #pragma unroll
            for (int d = 0; d < 64; d++) acc[d] += p * Vs[sl][d];
        }
    }
    float inv = 1.0f / l;
    float* op = attn_out + ((size_t)(bb * T_ + t)) * 1024 + head * 64;
    #pragma unroll
    for (int i = 0; i < 16; i++) {
        float4 o;
        o.x = acc[4*i+0] * inv;
        o.y = acc[4*i+1] * inv;
        o.z = acc[4*i+2] * inv;
        o.w = acc[4*i+3] * inv;
        *(float4*)(op + i * 4) = o;
    }
}

// ---------------------------------------------------------------------------
extern "C" void kernel_launch(void* const* d_in, const int* in_sizes, int n_in,
                              void* d_out, int out_size, void* d_ws, size_t ws_size,
                              hipStream_t stream) {
    const float* x   = (const float*)d_in[0];
    const float* Wq  = (const float*)d_in[1];
    const float* Wk  = (const float*)d_in[2];
    const float* Wv  = (const float*)d_in[3];
    const float* Wo  = (const float*)d_in[4];
    const float* bo  = (const float*)d_in[5];
    const float* W1  = (const float*)d_in[6];
    const float* b1  = (const float*)d_in[7];
    const float* W2  = (const float*)d_in[8];
    const float* b2  = (const float*)d_in[9];
    const float* g1  = (const float*)d_in[10];
    const float* be1 = (const float*)d_in[11];
    const float* g2  = (const float*)d_in[12];
    const float* be2 = (const float*)d_in[13];
    float* out = (float*)d_out;

    char* ws = (char*)d_ws;
    float* h    = (float*)(ws);                                  // 16 MB
    float* qkv  = (float*)(ws + ((size_t)16 << 20));             // 48 MB
    float* attn = (float*)(ws + ((size_t)64 << 20));             // 16 MB
    float* h2   = h;                                             // reuse
    float* ff1  = qkv;                                           // 64 MB (spans qkv+attn)

    // 1) h = LN(x)
    ln_kernel<<<dim3(BT_), dim3(256), 0, stream>>>(x, g1, be1, h);

    // 2) qkv = h @ [Wq|Wk|Wv]  (per-head batched: z = head)
    const float* Wqkv[3] = {Wq, Wk, Wv};
    for (int w = 0; w < 3; w++) {
        gemm_kernel<128, 64, 8, 4, 0><<<dim3(1, BT_/128, H_), dim3(256), 0, stream>>>(
            h, C_,
            Wqkv[w], HD_, (long)(C_ * HD_),
            qkv + w * 1024, 3 * C_, (long)HD_,
            nullptr, nullptr,
            BT_, HD_, C_);
    }

    // 3) attn = causal_softmax(q k^T / sqrt(64)) v , concat heads
    attn_kernel<<<dim3(T_/256, B_*H_), dim3(256), 0, stream>>>(qkv, attn);

    // 4) out = x + attn @ Wo + bo
    gemm_kernel<128, 128, 8, 8, 1|4><<<dim3(C_/128, BT_/128, 1), dim3(256), 0, stream>>>(
        attn, C_,
        Wo, C_, 0L,
        out, C_, 0L,
        bo, x,
        BT_, C_, C_);

    // 5) h2 = LN(out)
    ln_kernel<<<dim3(BT_), dim3(256), 0, stream>>>(out, g2, be2, h2);

    // 6) ff1 = relu(h2 @ W1 + b1)
    gemm_kernel<128, 128, 8, 8, 1|2><<<dim3(FF_/128, BT_/128, 1), dim3(256), 0, stream>>>(
        h2, C_,
        W1, FF_, 0L,
        ff1, FF_, 0L,
        b1, nullptr,
        BT_, FF_, C_);

    // 7) out = out + ff1 @ W2 + b2
    gemm_kernel<128, 128, 8, 8, 1|4><<<dim3(C_/128, BT_/128, 1), dim3(256), 0, stream>>>(
        ff1, FF_,
        W2, C_, 0L,
        out, C_, 0L,
        b2, out,
        BT_, C_, FF_);
}

// Round 2
// 1556.170 us; speedup vs baseline: 2.8137x; 2.8137x over previous
//
#include <hip/hip_runtime.h>
#include <hip/hip_bf16.h>
#include <cstdint>
#include <cstddef>

#define B_ 2
#define T_ 2048
#define C_ 1024
#define H_ 16
#define HD_ 64
#define FF_ 4096
#define BT_ (B_*T_)   // 4096 rows

typedef __attribute__((ext_vector_type(8))) short short8;
typedef __attribute__((ext_vector_type(4))) float f32x4;

// bf16 <-> f32 as raw bit ops (exact widen; RNE narrow)
__device__ __forceinline__ float bf2f(ushort u) {
    return __uint_as_float(((uint)u) << 16);
}
__device__ __forceinline__ ushort f2bf(float f) {
    uint x = __float_as_uint(f);
    return (ushort)((x + 0x7fffu + ((x >> 16) & 1u)) >> 16);
}
__device__ __forceinline__ void unpack2(uint u, float& a, float& b) {
    a = __uint_as_float(u << 16);
    b = __uint_as_float(u & 0xffff0000u);
}

#define GLDS16(g, l)                                                        \
    __builtin_amdgcn_global_load_lds(                                       \
        (const __attribute__((address_space(1))) void*)(g),                 \
        (__attribute__((address_space(3))) void*)(l), 16, 0, 0)

// ---------------------------------------------------------------------------
// LayerNorm: one block (256 threads) per row of C_=1024, fp32 in, bf16 out.
// ---------------------------------------------------------------------------
__global__ __launch_bounds__(256) void ln_kernel(const float* __restrict__ x,
                                                 const float* __restrict__ g,
                                                 const float* __restrict__ b,
                                                 ushort* __restrict__ out) {
    int row = blockIdx.x;
    int tid = threadIdx.x;
    const float* xr = x + (size_t)row * C_;
    float4 v = *(const float4*)(xr + tid * 4);
    float s = v.x + v.y + v.z + v.w;
    float q = v.x*v.x + v.y*v.y + v.z*v.z + v.w*v.w;
    #pragma unroll
    for (int off = 32; off > 0; off >>= 1) {
        s += __shfl_down(s, off);
        q += __shfl_down(q, off);
    }
    __shared__ float ss[4], qs[4];
    if ((tid & 63) == 0) { ss[tid >> 6] = s; qs[tid >> 6] = q; }
    __syncthreads();
    s = ss[0] + ss[1] + ss[2] + ss[3];
    q = qs[0] + qs[1] + qs[2] + qs[3];
    float mu  = s * (1.0f / C_);
    float var = q * (1.0f / C_) - mu * mu;
    float r = rsqrtf(var + 1e-5f);
    float4 gv = *(const float4*)(g + tid * 4);
    float4 bv = *(const float4*)(b + tid * 4);
    ushort4 o;
    o.x = f2bf((v.x - mu) * r * gv.x + bv.x);
    o.y = f2bf((v.y - mu) * r * gv.y + bv.y);
    o.z = f2bf((v.z - mu) * r * gv.z + bv.z);
    o.w = f2bf((v.w - mu) * r * gv.w + bv.w);
    *(ushort4*)(out + (size_t)row * C_ + tid * 4) = o;
}

// ---------------------------------------------------------------------------
// Tiled transpose + fp32->bf16 convert.
// in_z  = in  + z*in_bs   : [R][Cc] fp32 row-major
// out_z = out + z*out_bs  : [Cc][R] bf16, row stride ldo
// Block (32,8), each thread does 4 rows of a 32x32 tile. Dims % 32 == 0.
// ---------------------------------------------------------------------------
__global__ __launch_bounds__(256) void tcvt_kernel(const float* __restrict__ in,
                                                   ushort* __restrict__ out,
                                                   int R, int Cc, int ldo,
                                                   long in_bs, long out_bs) {
    __shared__ float tile[32][33];
    const float* inz = in + (size_t)blockIdx.z * in_bs;
    ushort* outz = out + (size_t)blockIdx.z * out_bs;
    int c0 = blockIdx.x * 32, r0 = blockIdx.y * 32;
    #pragma unroll
    for (int i = 0; i < 4; i++) {
        int r = threadIdx.y + i * 8;
        tile[r][threadIdx.x] = inz[(size_t)(r0 + r) * Cc + c0 + threadIdx.x];
    }
    __syncthreads();
    #pragma unroll
    for (int i = 0; i < 4; i++) {
        int c = threadIdx.y + i * 8;
        outz[(size_t)(c0 + c) * ldo + r0 + threadIdx.x] = f2bf(tile[threadIdx.x][c]);
    }
}

// ---------------------------------------------------------------------------
// bf16 MFMA GEMM, m97 structure: 128x128 tile, BK=32, 4 waves, each wave a
// 64x64 quadrant as 4x4 frags of mfma_f32_16x16x32_bf16.
// A [M][K] bf16, Bt [N][K] bf16 (B transposed). Staging via global_load_lds
// width=16 into linear LDS [128][32]; ds_read_b128 fragments.
// EPI bits: 1=bias(fp32 [N]), 2=relu, 4=residual(fp32 [M][N]).
// ---------------------------------------------------------------------------
template<int EPI, bool OUT_BF16>
__global__ __launch_bounds__(256) void gemm_bf16(
    const ushort* __restrict__ A,
    const ushort* __restrict__ Bt,
    void* __restrict__ Cout,
    const float* __restrict__ bias,
    const float* __restrict__ resid,
    int M, int N, int K)
{
    __shared__ ushort As[128 * 32];
    __shared__ ushort Bs[128 * 32];

    int tid  = threadIdx.x;
    int lane = tid & 63;
    int lr = lane & 15, lq = lane >> 4;
    int wave = tid >> 6;
    int wr = wave >> 1, wc = wave & 1;
    int m0 = blockIdx.y * 128, n0 = blockIdx.x * 128;

    f32x4 acc[4][4];
    #pragma unroll
    for (int m = 0; m < 4; m++)
        #pragma unroll
        for (int n = 0; n < 4; n++)
            acc[m][n] = {0.f, 0.f, 0.f, 0.f};

    // staging addresses: thread t covers row t/4 (+64 on 2nd issue), 8 bf16 at col (t&3)*8
    int arow = tid >> 2;
    int acol = (tid & 3) * 8;
    const ushort* ga = A  + (size_t)(m0 + arow) * K + acol;
    const ushort* gb = Bt + (size_t)(n0 + arow) * K + acol;
    int lbase = wave * 1024;   // per-wave uniform LDS byte base

    for (int k0 = 0; k0 < K; k0 += 32) {
        GLDS16(ga + k0,          (char*)As + lbase);
        GLDS16(ga + 64*(size_t)K + k0, (char*)As + 4096 + lbase);
        GLDS16(gb + k0,          (char*)Bs + lbase);
        GLDS16(gb + 64*(size_t)K + k0, (char*)Bs + 4096 + lbase);
        __syncthreads();   // drains vmcnt: staged data visible

        short8 a[4], b[4];
        #pragma unroll
        for (int m = 0; m < 4; m++)
            a[m] = *(const short8*)(As + (wr*64 + m*16 + lr) * 32 + lq*8);
        #pragma unroll
        for (int n = 0; n < 4; n++)
            b[n] = *(const short8*)(Bs + (wc*64 + n*16 + lr) * 32 + lq*8);
        #pragma unroll
        for (int m = 0; m < 4; m++)
            #pragma unroll
            for (int n = 0; n < 4; n++)
                acc[m][n] = __builtin_amdgcn_mfma_f32_16x16x32_bf16(
                    a[m], b[n], acc[m][n], 0, 0, 0);
        __syncthreads();   // before next overwrite of LDS
    }

    // epilogue: C/D layout col=lane&15, row=(lane>>4)*4+reg  [m89 verified]
    #pragma unroll
    for (int m = 0; m < 4; m++) {
        #pragma unroll
        for (int n = 0; n < 4; n++) {
            int col = n0 + wc*64 + n*16 + lr;
            #pragma unroll
            for (int j = 0; j < 4; j++) {
                int row = m0 + wr*64 + m*16 + lq*4 + j;
                float v = acc[m][n][j];
                if (EPI & 1) v += bias[col];
                if (EPI & 2) v = fmaxf(v, 0.f);
                if (EPI & 4) v += resid[(size_t)row * N + col];
                if (OUT_BF16)
                    ((ushort*)Cout)[(size_t)row * N + col] = f2bf(v);
                else
                    ((float*)Cout)[(size_t)row * N + col] = v;
            }
        }
    }
}

// ---------------------------------------------------------------------------
// Causal flash attention, fp32 math over bf16 qkv. One thread per query row.
// qkv: [BT_][3072] bf16; q at col h*64, k at 1024+h*64, v at 2048+h*64.
// out: [BT_][1024] bf16 (heads concatenated).
// ---------------------------------------------------------------------------
__global__ __launch_bounds__(256) void attn_kernel(const ushort* __restrict__ qkv,
                                                   ushort* __restrict__ attn_out) {
    int bh = blockIdx.y;          // 0..31
    int bb = bh >> 4;             // batch
    int head = bh & 15;
    int t = blockIdx.x * 256 + threadIdx.x;

    const ushort* qp = qkv + ((size_t)(bb * T_ + t)) * 3072 + head * 64;
    float q[64];
    #pragma unroll
    for (int i = 0; i < 8; i++) {
        uint4 u = *(const uint4*)(qp + i * 8);
        unpack2(u.x, q[8*i+0], q[8*i+1]);
        unpack2(u.y, q[8*i+2], q[8*i+3]);
        unpack2(u.z, q[8*i+4], q[8*i+5]);
        unpack2(u.w, q[8*i+6], q[8*i+7]);
    }
    #pragma unroll
    for (int d = 0; d < 64; d++) q[d] *= 0.125f;   // HD^-0.5

    float m = -INFINITY, l = 0.f;
    float acc[64];
    #pragma unroll
    for (int d = 0; d < 64; d++) acc[d] = 0.f;

    __shared__ float Ks[64][64];
    __shared__ float Vs[64][64];

    int nk = blockIdx.x * 256 + 256;   // keys needed by this block (<= T_)

    for (int s0 = 0; s0 < nk; s0 += 64) {
        __syncthreads();
        {
            int sr = threadIdx.x >> 2;           // 0..63
            int c16 = (threadIdx.x & 3) * 16;    // 0,16,32,48
            const ushort* kb = qkv + ((size_t)(bb * T_ + s0 + sr)) * 3072
                             + 1024 + head * 64 + c16;
            uint4 ka = *(const uint4*)kb;
            uint4 kc = *(const uint4*)(kb + 8);
            uint4 va = *(const uint4*)(kb + 1024);
            uint4 vc = *(const uint4*)(kb + 1032);
            float* kd = &Ks[sr][c16];
            float* vd = &Vs[sr][c16];
            unpack2(ka.x, kd[0], kd[1]);  unpack2(ka.y, kd[2], kd[3]);
            unpack2(ka.z, kd[4], kd[5]);  unpack2(ka.w, kd[6], kd[7]);
            unpack2(kc.x, kd[8], kd[9]);  unpack2(kc.y, kd[10], kd[11]);
            unpack2(kc.z, kd[12], kd[13]); unpack2(kc.w, kd[14], kd[15]);
            unpack2(va.x, vd[0], vd[1]);  unpack2(va.y, vd[2], vd[3]);
            unpack2(va.z, vd[4], vd[5]);  unpack2(va.w, vd[6], vd[7]);
            unpack2(vc.x, vd[8], vd[9]);  unpack2(vc.y, vd[10], vd[11]);
            unpack2(vc.z, vd[12], vd[13]); unpack2(vc.w, vd[14], vd[15]);
        }
        __syncthreads();
        int send = (nk - s0 < 64) ? (nk - s0) : 64;
        for (int sl = 0; sl < send; sl++) {
            if (s0 + sl > t) break;   // causal
            float p0 = 0.f, p1 = 0.f, p2 = 0.f, p3 = 0.f;
            #pragma unroll
            for (int d = 0; d < 64; d += 4) {
                p0 += q[d+0] * Ks[sl][d+0];
                p1 += q[d+1] * Ks[sl][d+1];
                p2 += q[d+2] * Ks[sl][d+2];
                p3 += q[d+3] * Ks[sl][d+3];
            }
            float sc = (p0 + p1) + (p2 + p3);
            if (sc > m) {               // rare rescale
                float corr = __expf(m - sc);
                m = sc;
                l *= corr;
                #pragma unroll
                for (int d = 0; d < 64; d++) acc[d] *= corr;
            }
            float p = __expf(sc - m);
            l += p;
            #pragma unroll
            for (int d = 0; d < 64; d++) acc[d] += p * Vs[sl][d];
        }
    }
    float inv = 1.0f / l;
    ushort* op = attn_out + ((size_t)(bb * T_ + t)) * 1024 + head * 64;
    #pragma unroll
    for (int i = 0; i < 16; i++) {
        ushort4 o;
        o.x = f2bf(acc[4*i+0] * inv);
        o.y = f2bf(acc[4*i+1] * inv);
        o.z = f2bf(acc[4*i+2] * inv);
        o.w = f2bf(acc[4*i+3] * inv);
        *(ushort4*)(op + i * 4) = o;
    }
}

// ---------------------------------------------------------------------------
extern "C" void kernel_launch(void* const* d_in, const int* in_sizes, int n_in,
                              void* d_out, int out_size, void* d_ws, size_t ws_size,
                              hipStream_t stream) {
    const float* x   = (const float*)d_in[0];
    const float* Wq  = (const float*)d_in[1];
    const float* Wk  = (const float*)d_in[2];
    const float* Wv  = (const float*)d_in[3];
    const float* Wo  = (const float*)d_in[4];
    const float* bo  = (const float*)d_in[5];
    const float* W1  = (const float*)d_in[6];
    const float* b1  = (const float*)d_in[7];
    const float* W2  = (const float*)d_in[8];
    const float* b2  = (const float*)d_in[9];
    const float* g1  = (const float*)d_in[10];
    const float* be1 = (const float*)d_in[11];
    const float* g2  = (const float*)d_in[12];
    const float* be2 = (const float*)d_in[13];
    float* out = (float*)d_out;

    char* ws = (char*)d_ws;
    const size_t MB = 1 << 20;
    ushort* h_bf    = (ushort*)(ws);                 // 8 MB  (h, later h2)
    ushort* qkv_act = (ushort*)(ws + 8*MB);          // 24 MB [4096][3072]
    ushort* attn_bf = (ushort*)(ws + 32*MB);         // 8 MB  [4096][1024]
    ushort* ff1     = (ushort*)(ws + 8*MB);          // 32 MB [4096][4096] (reuses qkv+attn)
    ushort* qkvw    = (ushort*)(ws + 40*MB);         // 6 MB  [3072][1024]
    ushort* Wo_t    = (ushort*)(ws + 46*MB);         // 2 MB  [1024][1024]
    ushort* W1_t    = (ushort*)(ws + 48*MB);         // 8 MB  [4096][1024]
    ushort* W2_t    = (ushort*)(ws + 56*MB);         // 8 MB  [1024][4096]

    // --- weight transposes + bf16 convert ---
    // Wq/Wk/Wv: per head slice [1024][64] -> rows (w*1024 + h*64 .. +64) of qkvw
    const float* Wsrc[3] = {Wq, Wk, Wv};
    for (int w = 0; w < 3; w++) {
        tcvt_kernel<<<dim3(2, 32, 16), dim3(32, 8), 0, stream>>>(
            Wsrc[w], qkvw + (size_t)w * 1024 * 1024,
            1024, 64, 1024, 65536L, 65536L);
    }
    tcvt_kernel<<<dim3(32, 32, 1), dim3(32, 8), 0, stream>>>(
        Wo, Wo_t, 1024, 1024, 1024, 0L, 0L);
    tcvt_kernel<<<dim3(128, 32, 1), dim3(32, 8), 0, stream>>>(
        W1, W1_t, 1024, 4096, 1024, 0L, 0L);
    tcvt_kernel<<<dim3(32, 128, 1), dim3(32, 8), 0, stream>>>(
        W2, W2_t, 4096, 1024, 4096, 0L, 0L);

    // 1) h = LN(x) -> bf16
    ln_kernel<<<dim3(BT_), dim3(256), 0, stream>>>(x, g1, be1, h_bf);

    // 2) qkv = h @ Wqkv^T   [4096][3072]
    gemm_bf16<0, true><<<dim3(3072/128, BT_/128), dim3(256), 0, stream>>>(
        h_bf, qkvw, qkv_act, nullptr, nullptr, BT_, 3072, C_);

    // 3) attention
    attn_kernel<<<dim3(T_/256, B_*H_), dim3(256), 0, stream>>>(qkv_act, attn_bf);

    // 4) out = x + attn @ Wo + bo   (fp32 out)
    gemm_bf16<1|4, false><<<dim3(1024/128, BT_/128), dim3(256), 0, stream>>>(
        attn_bf, Wo_t, out, bo, x, BT_, C_, C_);

    // 5) h2 = LN(out) -> bf16
    ln_kernel<<<dim3(BT_), dim3(256), 0, stream>>>(out, g2, be2, h_bf);

    // 6) ff1 = relu(h2 @ W1 + b1) -> bf16
    gemm_bf16<1|2, true><<<dim3(4096/128, BT_/128), dim3(256), 0, stream>>>(
        h_bf, W1_t, ff1, b1, nullptr, BT_, FF_, C_);

    // 7) out = out + ff1 @ W2 + b2  (fp32, residual = out itself)
    gemm_bf16<1|4, false><<<dim3(1024/128, BT_/128), dim3(256), 0, stream>>>(
        ff1, W2_t, out, b2, out, BT_, C_, FF_);
}

// Round 3
// 380.854 us; speedup vs baseline: 11.4967x; 4.0860x over previous
//
#include <hip/hip_runtime.h>
#include <hip/hip_bf16.h>
#include <cstdint>
#include <cstddef>

#define B_ 2
#define T_ 2048
#define C_ 1024
#define H_ 16
#define HD_ 64
#define FF_ 4096
#define BT_ (B_*T_)   // 4096 rows

typedef __attribute__((ext_vector_type(8))) short short8;
typedef __attribute__((ext_vector_type(4))) float f32x4;

__device__ __forceinline__ ushort f2bf(float f) {
    uint x = __float_as_uint(f);
    return (ushort)((x + 0x7fffu + ((x >> 16) & 1u)) >> 16);
}

#define GLDS16(g, l)                                                        \
    __builtin_amdgcn_global_load_lds(                                       \
        (const __attribute__((address_space(1))) void*)(g),                 \
        (__attribute__((address_space(3))) void*)(l), 16, 0, 0)

// ---------------------------------------------------------------------------
// LayerNorm: one block (256 threads) per row of C_=1024, fp32 in, bf16 out.
// ---------------------------------------------------------------------------
__global__ __launch_bounds__(256) void ln_kernel(const float* __restrict__ x,
                                                 const float* __restrict__ g,
                                                 const float* __restrict__ b,
                                                 ushort* __restrict__ out) {
    int row = blockIdx.x;
    int tid = threadIdx.x;
    const float* xr = x + (size_t)row * C_;
    float4 v = *(const float4*)(xr + tid * 4);
    float s = v.x + v.y + v.z + v.w;
    float q = v.x*v.x + v.y*v.y + v.z*v.z + v.w*v.w;
    #pragma unroll
    for (int off = 32; off > 0; off >>= 1) {
        s += __shfl_down(s, off);
        q += __shfl_down(q, off);
    }
    __shared__ float ss[4], qs[4];
    if ((tid & 63) == 0) { ss[tid >> 6] = s; qs[tid >> 6] = q; }
    __syncthreads();
    s = ss[0] + ss[1] + ss[2] + ss[3];
    q = qs[0] + qs[1] + qs[2] + qs[3];
    float mu  = s * (1.0f / C_);
    float var = q * (1.0f / C_) - mu * mu;
    float r = rsqrtf(var + 1e-5f);
    float4 gv = *(const float4*)(g + tid * 4);
    float4 bv = *(const float4*)(b + tid * 4);
    ushort4 o;
    o.x = f2bf((v.x - mu) * r * gv.x + bv.x);
    o.y = f2bf((v.y - mu) * r * gv.y + bv.y);
    o.z = f2bf((v.z - mu) * r * gv.z + bv.z);
    o.w = f2bf((v.w - mu) * r * gv.w + bv.w);
    *(ushort4*)(out + (size_t)row * C_ + tid * 4) = o;
}

// ---------------------------------------------------------------------------
// Tiled transpose + fp32->bf16 convert. (weights, once per call)
// ---------------------------------------------------------------------------
__global__ __launch_bounds__(256) void tcvt_kernel(const float* __restrict__ in,
                                                   ushort* __restrict__ out,
                                                   int R, int Cc, int ldo,
                                                   long in_bs, long out_bs) {
    __shared__ float tile[32][33];
    const float* inz = in + (size_t)blockIdx.z * in_bs;
    ushort* outz = out + (size_t)blockIdx.z * out_bs;
    int c0 = blockIdx.x * 32, r0 = blockIdx.y * 32;
    #pragma unroll
    for (int i = 0; i < 4; i++) {
        int r = threadIdx.y + i * 8;
        tile[r][threadIdx.x] = inz[(size_t)(r0 + r) * Cc + c0 + threadIdx.x];
    }
    __syncthreads();
    #pragma unroll
    for (int i = 0; i < 4; i++) {
        int c = threadIdx.y + i * 8;
        outz[(size_t)(c0 + c) * ldo + r0 + threadIdx.x] = f2bf(tile[threadIdx.x][c]);
    }
}

// ---------------------------------------------------------------------------
// bf16 MFMA GEMM (m97 structure): 128x128 tile, BK=32, 4 waves.
// A [M][K] bf16, Bt [N][K] bf16. EPI: 1=bias, 2=relu, 4=residual fp32.
// ---------------------------------------------------------------------------
template<int EPI, bool OUT_BF16>
__global__ __launch_bounds__(256) void gemm_bf16(
    const ushort* __restrict__ A,
    const ushort* __restrict__ Bt,
    void* __restrict__ Cout,
    const float* __restrict__ bias,
    const float* __restrict__ resid,
    int M, int N, int K)
{
    __shared__ ushort As[128 * 32];
    __shared__ ushort Bs[128 * 32];

    int tid  = threadIdx.x;
    int lane = tid & 63;
    int lr = lane & 15, lq = lane >> 4;
    int wave = tid >> 6;
    int wr = wave >> 1, wc = wave & 1;
    int m0 = blockIdx.y * 128, n0 = blockIdx.x * 128;

    f32x4 acc[4][4];
    #pragma unroll
    for (int m = 0; m < 4; m++)
        #pragma unroll
        for (int n = 0; n < 4; n++)
            acc[m][n] = {0.f, 0.f, 0.f, 0.f};

    int arow = tid >> 2;
    int acol = (tid & 3) * 8;
    const ushort* ga = A  + (size_t)(m0 + arow) * K + acol;
    const ushort* gb = Bt + (size_t)(n0 + arow) * K + acol;
    int lbase = wave * 1024;

    for (int k0 = 0; k0 < K; k0 += 32) {
        GLDS16(ga + k0,                (char*)As + lbase);
        GLDS16(ga + 64*(size_t)K + k0, (char*)As + 4096 + lbase);
        GLDS16(gb + k0,                (char*)Bs + lbase);
        GLDS16(gb + 64*(size_t)K + k0, (char*)Bs + 4096 + lbase);
        __syncthreads();

        short8 a[4], b[4];
        #pragma unroll
        for (int m = 0; m < 4; m++)
            a[m] = *(const short8*)(As + (wr*64 + m*16 + lr) * 32 + lq*8);
        #pragma unroll
        for (int n = 0; n < 4; n++)
            b[n] = *(const short8*)(Bs + (wc*64 + n*16 + lr) * 32 + lq*8);
        #pragma unroll
        for (int m = 0; m < 4; m++)
            #pragma unroll
            for (int n = 0; n < 4; n++)
                acc[m][n] = __builtin_amdgcn_mfma_f32_16x16x32_bf16(
                    a[m], b[n], acc[m][n], 0, 0, 0);
        __syncthreads();
    }

    #pragma unroll
    for (int m = 0; m < 4; m++) {
        #pragma unroll
        for (int n = 0; n < 4; n++) {
            int col = n0 + wc*64 + n*16 + lr;
            #pragma unroll
            for (int j = 0; j < 4; j++) {
                int row = m0 + wr*64 + m*16 + lq*4 + j;
                float v = acc[m][n][j];
                if (EPI & 1) v += bias[col];
                if (EPI & 2) v = fmaxf(v, 0.f);
                if (EPI & 4) v += resid[(size_t)row * N + col];
                if (OUT_BF16)
                    ((ushort*)Cout)[(size_t)row * N + col] = f2bf(v);
                else
                    ((float*)Cout)[(size_t)row * N + col] = v;
            }
        }
    }
}

// ---------------------------------------------------------------------------
// MFMA causal flash attention.
// qk : [BT_][2048] bf16 (q at h*64, k at 1024+h*64)
// vt : [1024][4096] bf16 = V^T, row = h*64+d, col = bb*2048+s
// out: [BT_][1024] bf16
// Block: 256 thr = 4 waves; Q-tile 128 rows (wave w: rows qw..qw+31 as 2
// 16-row fragments). K-tile 64 keys. K and V^T staged in XOR-swizzled LDS
// via pre-swizzled-source global_load_lds; P via per-wave swizzled LDS.
// ---------------------------------------------------------------------------
__global__ __launch_bounds__(256) void attn_mfma(const ushort* __restrict__ qk,
                                                 const ushort* __restrict__ vt,
                                                 ushort* __restrict__ attn_out) {
    int bh = blockIdx.y;
    int bb = bh >> 4;
    int head = bh & 15;
    int qa = 15 - blockIdx.x;          // heavy tiles first
    int q0 = qa * 128;

    int tid  = threadIdx.x;
    int lane = tid & 63;
    int lr = lane & 15, lq = lane >> 4;
    int wave = tid >> 6;
    int qw = q0 + wave * 32;

    __shared__ ushort Ks[64 * 64];     // [s][d], 16B-slot XOR-swizzled
    __shared__ ushort Vs[64 * 64];     // [d][s], swizzled
    __shared__ ushort Ps[4][32 * 64];  // per-wave P, swizzled

    // Q fragments, held in registers for the whole block
    short8 qf[2][2];
    {
        const ushort* qb = qk + ((size_t)(bb * T_ + qw)) * 2048 + head * 64;
        #pragma unroll
        for (int mt = 0; mt < 2; mt++)
            #pragma unroll
            for (int kk = 0; kk < 2; kk++)
                qf[mt][kk] = *(const short8*)(qb + (size_t)(mt*16 + lr) * 2048 + kk*32 + lq*8);
    }

    f32x4 acc[2][4];
    float mrow[2][4], lsum[2][4];
    #pragma unroll
    for (int mt = 0; mt < 2; mt++) {
        #pragma unroll
        for (int dt = 0; dt < 4; dt++) acc[mt][dt] = {0.f, 0.f, 0.f, 0.f};
        #pragma unroll
        for (int j = 0; j < 4; j++) { mrow[mt][j] = -INFINITY; lsum[mt][j] = 0.f; }
    }

    // staging geometry: thread t covers row t/8, 16B slot t%8 (linear LDS);
    // source column pre-swizzled so LDS[r][slot c] = data[r][col8 = c ^ (r&7)]
    int srow = tid >> 3;
    int sc = ((tid & 7) ^ (srow & 7)) * 8;
    const ushort* kg0 = qk + ((size_t)(bb * T_ + srow)) * 2048 + 1024 + head * 64 + sc;
    const ushort* vg0 = vt + ((size_t)(head * 64 + srow)) * 4096 + (size_t)bb * T_ + sc;

    int nt = q0 / 64 + 2;
    for (int it = 0; it < nt; it++) {
        int s0 = it * 64;
        __syncthreads();   // previous-iteration LDS reads done
        GLDS16(kg0 + (size_t)s0 * 2048,            (char*)Ks + wave * 1024);
        GLDS16(kg0 + (size_t)(s0 + 32) * 2048,     (char*)Ks + 4096 + wave * 1024);
        GLDS16(vg0 + s0,                            (char*)Vs + wave * 1024);
        GLDS16(vg0 + (size_t)32 * 4096 + s0,        (char*)Vs + 4096 + wave * 1024);
        __syncthreads();   // drains vmcnt: tiles visible

        if (s0 <= qw + 31) {   // wave-uniform causal skip
            // ---- S = Q K^T ----
            short8 kf[4][2];
            #pragma unroll
            for (int n = 0; n < 4; n++) {
                int row = n*16 + lr;
                #pragma unroll
                for (int kk = 0; kk < 2; kk++)
                    kf[n][kk] = *(const short8*)((const char*)Ks + row*128
                                 + (((kk*4 + lq) ^ (row & 7)) << 4));
            }
            f32x4 sa[2][4];
            #pragma unroll
            for (int mt = 0; mt < 2; mt++)
                #pragma unroll
                for (int n = 0; n < 4; n++) {
                    sa[mt][n] = {0.f, 0.f, 0.f, 0.f};
                    #pragma unroll
                    for (int kk = 0; kk < 2; kk++)
                        sa[mt][n] = __builtin_amdgcn_mfma_f32_16x16x32_bf16(
                            qf[mt][kk], kf[n][kk], sa[mt][n], 0, 0, 0);
                }

            // ---- online softmax (lane-parallel; reduce over 16-lane col group)
            char* pw = (char*)Ps[wave];
            #pragma unroll
            for (int mt = 0; mt < 2; mt++) {
                #pragma unroll
                for (int j = 0; j < 4; j++) {
                    int qrow = qw + mt*16 + lq*4 + j;
                    float vmax = -INFINITY;
                    #pragma unroll
                    for (int n = 0; n < 4; n++) {
                        int scol = s0 + n*16 + lr;
                        float v = (scol <= qrow) ? sa[mt][n][j] * 0.125f : -INFINITY;
                        sa[mt][n][j] = v;
                        vmax = fmaxf(vmax, v);
                    }
                    #pragma unroll
                    for (int off = 1; off < 16; off <<= 1)
                        vmax = fmaxf(vmax, __shfl_xor(vmax, off));
                    float mnew = fmaxf(mrow[mt][j], vmax);
                    float corr = __expf(mrow[mt][j] - mnew);
                    mrow[mt][j] = mnew;
                    float rsum = 0.f;
                    #pragma unroll
                    for (int n = 0; n < 4; n++) {
                        float p = __expf(sa[mt][n][j] - mnew);
                        sa[mt][n][j] = p;
                        rsum += p;
                    }
                    #pragma unroll
                    for (int off = 1; off < 16; off <<= 1)
                        rsum += __shfl_xor(rsum, off);
                    lsum[mt][j] = lsum[mt][j] * corr + rsum;
                    #pragma unroll
                    for (int dt = 0; dt < 4; dt++)
                        acc[mt][dt][j] *= corr;
                }
            }

            // ---- P -> bf16 -> per-wave swizzled LDS ----
            #pragma unroll
            for (int mt = 0; mt < 2; mt++)
                #pragma unroll
                for (int n = 0; n < 4; n++)
                    #pragma unroll
                    for (int j = 0; j < 4; j++) {
                        int row = mt*16 + lq*4 + j;
                        int col = n*16 + lr;
                        int byte = row*128 + (((col >> 3) ^ (row & 7)) << 4) + (col & 7)*2;
                        *(ushort*)(pw + byte) = f2bf(sa[mt][n][j]);
                    }

            // ---- O += P V ----
            short8 vf[4][2], pf[2][2];
            #pragma unroll
            for (int dt = 0; dt < 4; dt++) {
                int row = dt*16 + lr;
                #pragma unroll
                for (int kk = 0; kk < 2; kk++)
                    vf[dt][kk] = *(const short8*)((const char*)Vs + row*128
                                  + (((kk*4 + lq) ^ (row & 7)) << 4));
            }
            #pragma unroll
            for (int mt = 0; mt < 2; mt++) {
                int row = mt*16 + lr;
                #pragma unroll
                for (int kk = 0; kk < 2; kk++)
                    pf[mt][kk] = *(const short8*)(pw + row*128
                                  + (((kk*4 + lq) ^ (row & 7)) << 4));
            }
            #pragma unroll
            for (int mt = 0; mt < 2; mt++)
                #pragma unroll
                for (int dt = 0; dt < 4; dt++)
                    #pragma unroll
                    for (int kk = 0; kk < 2; kk++)
                        acc[mt][dt] = __builtin_amdgcn_mfma_f32_16x16x32_bf16(
                            pf[mt][kk], vf[dt][kk], acc[mt][dt], 0, 0, 0);
        }
    }

    // ---- epilogue: O / l ----
    ushort* ob = attn_out + ((size_t)(bb * T_ + qw)) * 1024 + head * 64;
    #pragma unroll
    for (int mt = 0; mt < 2; mt++)
        #pragma unroll
        for (int j = 0; j < 4; j++) {
            float inv = 1.0f / lsum[mt][j];
            #pragma unroll
            for (int dt = 0; dt < 4; dt++)
                ob[(size_t)(mt*16 + lq*4 + j) * 1024 + dt*16 + lr] =
                    f2bf(acc[mt][dt][j] * inv);
        }
}

// ---------------------------------------------------------------------------
extern "C" void kernel_launch(void* const* d_in, const int* in_sizes, int n_in,
                              void* d_out, int out_size, void* d_ws, size_t ws_size,
                              hipStream_t stream) {
    const float* x   = (const float*)d_in[0];
    const float* Wq  = (const float*)d_in[1];
    const float* Wk  = (const float*)d_in[2];
    const float* Wv  = (const float*)d_in[3];
    const float* Wo  = (const float*)d_in[4];
    const float* bo  = (const float*)d_in[5];
    const float* W1  = (const float*)d_in[6];
    const float* b1  = (const float*)d_in[7];
    const float* W2  = (const float*)d_in[8];
    const float* b2  = (const float*)d_in[9];
    const float* g1  = (const float*)d_in[10];
    const float* be1 = (const float*)d_in[11];
    const float* g2  = (const float*)d_in[12];
    const float* be2 = (const float*)d_in[13];
    float* out = (float*)d_out;

    char* ws = (char*)d_ws;
    const size_t MB = 1 << 20;
    ushort* h_bf    = (ushort*)(ws);                 // 8 MB
    ushort* qk_act  = (ushort*)(ws + 8*MB);          // 16 MB [4096][2048]
    ushort* vt      = (ushort*)(ws + 24*MB);         // 8 MB  [1024][4096] V^T
    ushort* attn_bf = (ushort*)(ws + 32*MB);         // 8 MB  [4096][1024]
    ushort* ff1     = (ushort*)(ws + 8*MB);          // 32 MB (reuses qk/vt/attn)
    ushort* qkvw    = (ushort*)(ws + 40*MB);         // 6 MB  [3072][1024]
    ushort* Wo_t    = (ushort*)(ws + 46*MB);         // 2 MB
    ushort* W1_t    = (ushort*)(ws + 48*MB);         // 8 MB
    ushort* W2_t    = (ushort*)(ws + 56*MB);         // 8 MB

    // --- weight transposes + bf16 convert ---
    const float* Wsrc[3] = {Wq, Wk, Wv};
    for (int w = 0; w < 3; w++) {
        tcvt_kernel<<<dim3(2, 32, 16), dim3(32, 8), 0, stream>>>(
            Wsrc[w], qkvw + (size_t)w * 1024 * 1024,
            1024, 64, 1024, 65536L, 65536L);
    }
    tcvt_kernel<<<dim3(32, 32, 1), dim3(32, 8), 0, stream>>>(
        Wo, Wo_t, 1024, 1024, 1024, 0L, 0L);
    tcvt_kernel<<<dim3(128, 32, 1), dim3(32, 8), 0, stream>>>(
        W1, W1_t, 1024, 4096, 1024, 0L, 0L);
    tcvt_kernel<<<dim3(32, 128, 1), dim3(32, 8), 0, stream>>>(
        W2, W2_t, 4096, 1024, 4096, 0L, 0L);

    // 1) h = LN(x) -> bf16
    ln_kernel<<<dim3(BT_), dim3(256), 0, stream>>>(x, g1, be1, h_bf);

    // 2a) qk = h @ [Wq|Wk]^T   [4096][2048]
    gemm_bf16<0, true><<<dim3(2048/128, BT_/128), dim3(256), 0, stream>>>(
        h_bf, qkvw, qk_act, nullptr, nullptr, BT_, 2048, C_);
    // 2b) vt = Wv^T-rows @ h^T  -> V^T [1024][4096]  (swapped operands)
    gemm_bf16<0, true><<<dim3(BT_/128, 1024/128), dim3(256), 0, stream>>>(
        qkvw + (size_t)2*1024*1024, h_bf, vt, nullptr, nullptr, 1024, BT_, C_);

    // 3) attention (MFMA flash)
    attn_mfma<<<dim3(T_/128, B_*H_), dim3(256), 0, stream>>>(qk_act, vt, attn_bf);

    // 4) out = x + attn @ Wo + bo   (fp32 out)
    gemm_bf16<1|4, false><<<dim3(1024/128, BT_/128), dim3(256), 0, stream>>>(
        attn_bf, Wo_t, out, bo, x, BT_, C_, C_);

    // 5) h2 = LN(out) -> bf16
    ln_kernel<<<dim3(BT_), dim3(256), 0, stream>>>(out, g2, be2, h_bf);

    // 6) ff1 = relu(h2 @ W1 + b1) -> bf16
    gemm_bf16<1|2, true><<<dim3(4096/128, BT_/128), dim3(256), 0, stream>>>(
        h_bf, W1_t, ff1, b1, nullptr, BT_, FF_, C_);

    // 7) out = out + ff1 @ W2 + b2  (fp32, residual = out itself)
    gemm_bf16<1|4, false><<<dim3(1024/128, BT_/128), dim3(256), 0, stream>>>(
        ff1, W2_t, out, b2, out, BT_, C_, FF_);
}